// Round 3
// baseline (529.373 us; speedup 1.0000x reference)
//
#include <hip/hip_runtime.h>
#include <hip/hip_bf16.h>

#define T_SEQ 2048
#define DMODEL 4096
#define NH 32
#define NKV 8
#define HD 128
#define RVIRT 128
#define TKV (RVIRT + T_SEQ)   // 2176

typedef __attribute__((ext_vector_type(8))) short s16x8;
typedef __attribute__((ext_vector_type(4))) short s16x4;
typedef __attribute__((ext_vector_type(4))) float f32x4;
typedef __attribute__((ext_vector_type(4))) float float4v;

static __device__ __forceinline__ short f2bf(float f) {
  union { __hip_bfloat16 h; short s; } u; u.h = __float2bfloat16(f); return u.s;
}

static __device__ __forceinline__ void gload16(const void* g, void* l) {
  __builtin_amdgcn_global_load_lds(
      (const __attribute__((address_space(1))) void*)g,
      (__attribute__((address_space(3))) void*)l, 16, 0, 0);
}

// ---------------------------------------------------------------------------
// fp32 -> bf16 convert (X). Each thread converts 8 elements.
// ---------------------------------------------------------------------------
__global__ __launch_bounds__(256) void convert_x(const float* __restrict__ src,
                                                 short* __restrict__ dst)
{
  int i = (blockIdx.x * 256 + threadIdx.x) * 8;
  float4v a = *(const float4v*)(src + i);
  float4v b = *(const float4v*)(src + i + 4);
  s16x8 o;
#pragma unroll
  for (int j = 0; j < 4; ++j) { o[j] = f2bf(a[j]); o[4 + j] = f2bf(b[j]); }
  *(s16x8*)(dst + i) = o;
}

// ---------------------------------------------------------------------------
// Transpose + convert: src [K][N] fp32 -> dst [N][K] bf16. 64x64 tiles.
// ---------------------------------------------------------------------------
__global__ __launch_bounds__(256) void transpose_convert(const float* __restrict__ src,
    short* __restrict__ dst, int K, int N)
{
  __shared__ float tile[64][65];
  const int k0 = blockIdx.y * 64, n0 = blockIdx.x * 64;
  const int tid = threadIdx.x;
  const int rr = tid >> 4, c4 = (tid & 15) * 4;
#pragma unroll
  for (int it = 0; it < 4; ++it) {
    int row = it * 16 + rr;
    float4v v = *(const float4v*)(src + (size_t)(k0 + row) * N + n0 + c4);
    tile[row][c4] = v[0]; tile[row][c4 + 1] = v[1];
    tile[row][c4 + 2] = v[2]; tile[row][c4 + 3] = v[3];
  }
  __syncthreads();
  const int n = tid >> 3, seg = tid & 7;
#pragma unroll
  for (int it = 0; it < 2; ++it) {
    int nn = it * 32 + n;
    s16x8 o;
#pragma unroll
    for (int j = 0; j < 8; ++j) o[j] = f2bf(tile[seg * 8 + j][nn]);
    *(s16x8*)(dst + (size_t)(n0 + nn) * K + k0 + seg * 8) = o;
  }
}

// ---------------------------------------------------------------------------
// gemm128: C[M][N] = A[M][K] (bf16) x Bt[N][K] (bf16, B^T).
// m97/m103 structure (874-912 TF ref): 128x128 tile, BK=32, 256 threads
// (4 waves, 2x2), 3-slot LDS ring (48 KB -> 3 blocks/CU for cross-block
// latency hiding), 1 barrier + 1 counted vmcnt per K-step, width-16
// global_load_lds staging, linear conflict-free fragment layout.
//  - Ring-3 safety: STAGE(t+2) writes slot (t-1)%3; the top-of-step barrier
//    guarantees all waves finished step t-1 reads (compiler lgkmcnt before
//    MFMA use -> reads complete before the wave reaches the barrier).
//  - vmcnt(4) at top of step t drains stage(t) (4 loads/wave in flight for
//    t+1), vmcnt(0) on the last step.
// ---------------------------------------------------------------------------
template<int EPI>
__global__ __launch_bounds__(256, 3) void gemm128(const short* __restrict__ Ab,
    const short* __restrict__ Btb, float* __restrict__ C0,
    float* __restrict__ Ck, short* __restrict__ Cv, int M, int N, int K)
{
  constexpr int SLOT = 16384;             // A 8 KB + B 8 KB
  __shared__ __align__(16) char lds[3 * SLOT];
  const int tid = threadIdx.x, lane = tid & 63, w = tid >> 6;
  const int lo = lane & 15, g = lane >> 4;
  const int wm = w >> 1, wn = w & 1;
  const int m0 = blockIdx.y * 128, n0 = blockIdx.x * 128;
  const int NT = K >> 5;

  // wave w stages A chunks {2w, 2w+1} (rows w*32+lo, +16) and same for B
  const short* Asrc = Ab + (size_t)(m0 + w * 32 + lo) * K + g * 8;
  const short* Bsrc = Btb + (size_t)(n0 + w * 32 + lo) * K + g * 8;

  auto STAGE = [&](int y, int sl) {
    char* sb = lds + sl * SLOT;
    const int k0 = y * 32;
    gload16(Asrc + k0,                  sb + (w * 2) * 1024);
    gload16(Asrc + (size_t)16 * K + k0, sb + (w * 2 + 1) * 1024);
    gload16(Bsrc + k0,                  sb + 8192 + (w * 2) * 1024);
    gload16(Bsrc + (size_t)16 * K + k0, sb + 8192 + (w * 2 + 1) * 1024);
  };

  f32x4 acc[4][4];
#pragma unroll
  for (int i = 0; i < 4; ++i)
#pragma unroll
    for (int j = 0; j < 4; ++j) acc[i][j] = (f32x4){0.f, 0.f, 0.f, 0.f};

  STAGE(0, 0); STAGE(1, 1);
  int st = 0, s2 = 2;
  for (int t = 0; t < NT; ++t) {
    if (t + 1 < NT) asm volatile("s_waitcnt vmcnt(4)" ::: "memory");
    else            asm volatile("s_waitcnt vmcnt(0)" ::: "memory");
    __builtin_amdgcn_s_barrier();
    __builtin_amdgcn_sched_barrier(0);
    if (t + 2 < NT) STAGE(t + 2, s2);
    const char* sb = lds + st * SLOT;
    s16x8 af[4], bfv[4];
#pragma unroll
    for (int i = 0; i < 4; ++i)
      af[i] = *(const s16x8*)(sb + (wm * 4 + i) * 1024 + lane * 16);
#pragma unroll
    for (int j = 0; j < 4; ++j)
      bfv[j] = *(const s16x8*)(sb + 8192 + (wn * 4 + j) * 1024 + lane * 16);
#pragma unroll
    for (int i = 0; i < 4; ++i)
#pragma unroll
      for (int j = 0; j < 4; ++j)
        acc[i][j] = __builtin_amdgcn_mfma_f32_16x16x32_bf16(af[i], bfv[j], acc[i][j], 0, 0, 0);
    st = (st == 2) ? 0 : st + 1;
    s2 = (s2 == 2) ? 0 : s2 + 1;
  }

#pragma unroll
  for (int i = 0; i < 4; ++i)
#pragma unroll
    for (int j = 0; j < 4; ++j)
#pragma unroll
      for (int r = 0; r < 4; ++r) {
        int row = m0 + wm * 64 + i * 16 + g * 4 + r;
        int col = n0 + wn * 64 + j * 16 + lo;
        float val = acc[i][j][r];
        if (EPI == 0) {
          C0[(size_t)row * N + col] = val;
        } else {
          if (col < 4096) C0[(size_t)row * 4096 + col] = val;
          else if (col < 5120) Ck[(size_t)row * 1024 + (col - 4096)] = val;
          else {
            int vcol = col - 5120;
            Cv[(size_t)((vcol >> 7) * HD + (vcol & 127)) * TKV + RVIRT + row] = f2bf(val);
          }
        }
      }
}

// ---------------------------------------------------------------------------
// RMSNorm + RoPE. One wave per (t, head). qs folds 1/sqrt(HD) into Q.
// ---------------------------------------------------------------------------
__global__ __launch_bounds__(256) void rope_kernel(const float* __restrict__ proj,
    const float* __restrict__ nw, const float* __restrict__ cosT,
    const float* __restrict__ sinT, short* __restrict__ out,
    int nh_shift, int rows_total, int row0, float qs)
{
  int wid = blockIdx.x * 4 + (threadIdx.x >> 6);
  int lane = threadIdx.x & 63;
  int nh = 1 << nh_shift;
  int t = wid >> nh_shift;
  int hh = wid & (nh - 1);
  const float* src = proj + (size_t)t * (nh * HD) + hh * HD;
  float x1 = src[lane];
  float x2 = src[lane + 64];
  float ss = x1 * x1 + x2 * x2;
#pragma unroll
  for (int off = 32; off > 0; off >>= 1) ss += __shfl_xor(ss, off, 64);
  float rms = rsqrtf(ss * (1.0f / 128.0f) + 1e-6f);
  float n1 = x1 * rms * nw[lane];
  float n2 = x2 * rms * nw[lane + 64];
  float c1 = cosT[t * HD + lane], c2 = cosT[t * HD + lane + 64];
  float s1 = sinT[t * HD + lane], s2 = sinT[t * HD + lane + 64];
  short* dst = out + ((size_t)hh * rows_total + row0 + t) * HD;
  dst[lane]      = f2bf((n1 * c1 - n2 * s1) * qs);
  dst[lane + 64] = f2bf((n2 * c2 + n1 * s2) * qs);
}

// ---------------------------------------------------------------------------
// Virtual KV injection.
// ---------------------------------------------------------------------------
__global__ __launch_bounds__(256) void inject_kernel(const float* __restrict__ vk,
    const float* __restrict__ vv, const float* __restrict__ logit,
    short* __restrict__ Kr, short* __restrict__ Vt)
{
  int idx = blockIdx.x * 256 + threadIdx.x;   // < 8*128*128
  float alpha = 0.5f / (1.0f + __expf(-logit[0]));
  int kv = idx >> 14, rem = idx & 16383, r = rem >> 7, d = rem & 127;
  Kr[((size_t)kv * TKV + r) * HD + d] = f2bf(vk[idx] * alpha);
  Vt[((size_t)kv * HD + d) * TKV + r] = f2bf(vv[idx] * alpha);
}

// ---------------------------------------------------------------------------
// Flash attention v4 = r5's staged structure + r6's cheap softmax.
//  - K/V tiles staged in LDS (reg-staged, async split: issue loads for tile
//    t+1 before computing tile t; ds_write after the barrier). 2 barriers/tile.
//  - Swapped QK^T: S^T = mfma(K_frag, Q_frag); lane owns q-column (q = lo);
//    m,l per-lane scalars; max/sum = 16 local ops + 2 shfl_xor.
//  - Defer-max (THR=8): O-rescale only when tile max grows > 8.
//  - P packed 4xbf16 ds_write_b64 into per-wave LDS in PV A-operand layout.
//  - Mask only the diagonal tile; Q pre-scaled by 1/sqrt(HD).
//  - q-tile pairing (bx, 31-bx) for causal load balance.
// ---------------------------------------------------------------------------
template<bool MASKED>
static __device__ __forceinline__ void attn_tile(
    const s16x8* qf, float& m, float& l, f32x4* o,
    const char* Ksb, const char* Vsb, char* Psw,
    int kvt, int qr, int lo, int g)
{
  // S^T: sfr[cj][r] = S[k = kvt*64 + cj*16 + g*4 + r][q = lo]
  f32x4 sfr[4];
#pragma unroll
  for (int cj = 0; cj < 4; ++cj) {
    f32x4 z = {};
    const int kr = cj * 16 + lo;
#pragma unroll
    for (int kk = 0; kk < 4; ++kk) {
      s16x8 kf = *(const s16x8*)(Ksb + ((kr * 256 + kk * 64 + g * 16) ^ ((kr & 7) << 4)));
      z = __builtin_amdgcn_mfma_f32_16x16x32_bf16(kf, qf[kk], z, 0, 0, 0);
    }
    sfr[cj] = z;
  }
  float mx = -3.0e38f;
#pragma unroll
  for (int cj = 0; cj < 4; ++cj)
#pragma unroll
    for (int r = 0; r < 4; ++r) {
      float s = sfr[cj][r];
      if (MASKED) {
        int k = kvt * 64 + cj * 16 + g * 4 + r;
        bool ok = (k < RVIRT) || (k - RVIRT <= qr);
        s = ok ? s : -3.0e38f;
        sfr[cj][r] = s;
      }
      mx = fmaxf(mx, s);
    }
  mx = fmaxf(mx, __shfl_xor(mx, 16, 64));
  mx = fmaxf(mx, __shfl_xor(mx, 32, 64));
  if (__any(mx > m + 8.0f)) {           // defer-max
    float mnew = fmaxf(m, mx);
    float fs = __expf(m - mnew);
    m = mnew;
    l *= fs;
#pragma unroll
    for (int r = 0; r < 4; ++r) {
      float fsq = __shfl(fs, g * 4 + r, 64);
#pragma unroll
      for (int dj = 0; dj < 8; ++dj) o[dj][r] *= fsq;
    }
  }
  float rowsum = 0.f;
#pragma unroll
  for (int cj = 0; cj < 4; ++cj) {
    s16x4 pk;
#pragma unroll
    for (int r = 0; r < 4; ++r) {
      float pv = __expf(sfr[cj][r] - m);   // masked lanes: exp(-inf) = 0
      rowsum += pv;
      pk[r] = f2bf(pv);
    }
    *(s16x4*)(Psw + ((lo * 128 + cj * 32 + g * 8) ^ ((lo & 7) << 4))) = pk;
  }
  rowsum += __shfl_xor(rowsum, 16, 64);
  rowsum += __shfl_xor(rowsum, 32, 64);
  l += rowsum;
  // PV: pf (A-layout) from per-wave LDS; vf from Vs LDS
  s16x8 pf[2];
#pragma unroll
  for (int k2 = 0; k2 < 2; ++k2)
    pf[k2] = *(const s16x8*)(Psw + ((lo * 128 + k2 * 64 + g * 16) ^ ((lo & 7) << 4)));
#pragma unroll
  for (int dj = 0; dj < 8; ++dj) {
    const int d = dj * 16 + lo;
    const int vswz = ((d ^ (d >> 3)) & 7) << 4;
#pragma unroll
    for (int k2 = 0; k2 < 2; ++k2) {
      s16x8 vf = *(const s16x8*)(Vsb + ((d * 128 + k2 * 64 + g * 16) ^ vswz));
      o[dj] = __builtin_amdgcn_mfma_f32_16x16x32_bf16(pf[k2], vf, o[dj], 0, 0, 0);
    }
  }
}

__global__ __launch_bounds__(256) void attn_kernel(const short* __restrict__ Qr,
    const short* __restrict__ Kr, const short* __restrict__ Vt,
    short* __restrict__ out)
{
  __shared__ short Ks[64 * 128];                // (r*256 + c*16) ^ ((r&7)<<4)
  __shared__ short Vs[128 * 64];                // (d*128 + c8*16) ^ (((d^(d>>3))&7)<<4)
  __shared__ __align__(16) char Ps[4 * 4096];   // per wave: 2KB A-set + 2KB B-set
  const int tid = threadIdx.x, lane = tid & 63, w = tid >> 6;
  const int h = blockIdx.y, kvh = h >> 2, bx = blockIdx.x;
  const int lo = lane & 15, g = lane >> 4;
  const int q0A = bx * 64, q0B = (31 - bx) * 64;
  char* PsA = Ps + w * 4096;
  char* PsB = PsA + 2048;
  const short* Kb = Kr + (size_t)kvh * TKV * HD;
  const short* Vb = Vt + (size_t)kvh * HD * TKV;

  s16x8 qfA[4], qfB[4];
#pragma unroll
  for (int kk = 0; kk < 4; ++kk) {
    qfA[kk] = *(const s16x8*)(Qr + ((size_t)h * T_SEQ + q0A + w * 16 + lo) * HD + kk * 32 + g * 8);
    qfB[kk] = *(const s16x8*)(Qr + ((size_t)h * T_SEQ + q0B + w * 16 + lo) * HD + kk * 32 + g * 8);
  }

  float mA = -3.0e38f, lA = 0.f, mB = -3.0e38f, lB = 0.f;
  f32x4 oA[8] = {}, oB[8] = {};
  const int ntA = bx + 3, ntB = 34 - bx;
  const int qrA = q0A + w * 16 + lo, qrB = q0B + w * 16 + lo;

  s16x8 kst[4], vst[4];
  auto ISSUE = [&](int kvt) {
#pragma unroll
    for (int p = 0; p < 4; ++p) {
      int ci = p * 256 + tid;
      kst[p] = *(const s16x8*)(Kb + (size_t)(kvt * 64 + (ci >> 4)) * HD + (ci & 15) * 8);
      vst[p] = *(const s16x8*)(Vb + (size_t)(ci >> 3) * TKV + kvt * 64 + (ci & 7) * 8);
    }
  };
  auto WRITE = [&]() {
#pragma unroll
    for (int p = 0; p < 4; ++p) {
      int ci = p * 256 + tid;
      int r = ci >> 4, c = ci & 15;
      *(s16x8*)((char*)Ks + ((r * 256 + c * 16) ^ ((r & 7) << 4))) = kst[p];
      int d = ci >> 3, c8 = ci & 7;
      *(s16x8*)((char*)Vs + ((d * 128 + c8 * 16) ^ (((d ^ (d >> 3)) & 7) << 4))) = vst[p];
    }
  };

  ISSUE(0);
  WRITE();
  __syncthreads();

  for (int kvt = 0; kvt < ntB; ++kvt) {
    if (kvt + 1 < ntB) ISSUE(kvt + 1);      // loads fly during compute
    if (kvt < ntA) {
      if (kvt == ntA - 1) attn_tile<true >(qfA, mA, lA, oA, (const char*)Ks, (const char*)Vs, PsA, kvt, qrA, lo, g);
      else                attn_tile<false>(qfA, mA, lA, oA, (const char*)Ks, (const char*)Vs, PsA, kvt, qrA, lo, g);
    }
    if (kvt == ntB - 1)   attn_tile<true >(qfB, mB, lB, oB, (const char*)Ks, (const char*)Vs, PsB, kvt, qrB, lo, g);
    else                  attn_tile<false>(qfB, mB, lB, oB, (const char*)Ks, (const char*)Vs, PsB, kvt, qrB, lo, g);
    __syncthreads();                         // all waves done reading tile kvt
    if (kvt + 1 < ntB) WRITE();              // waits vmcnt via reg dependence
    __syncthreads();                         // writes visible
  }
  // epilogue: o row q = g*4 + r; l lives on lane with lo == q (any g)
#pragma unroll
  for (int r = 0; r < 4; ++r) {
    float lqA = __shfl(lA, g * 4 + r, 64);
    float lqB = __shfl(lB, g * 4 + r, 64);
    float iA = 1.f / lqA, iB = 1.f / lqB;
#pragma unroll
    for (int dj = 0; dj < 8; ++dj) {
      int col = h * HD + dj * 16 + lo;
      int rowA = q0A + w * 16 + g * 4 + r;
      int rowB = q0B + w * 16 + g * 4 + r;
      out[(size_t)rowA * (NH * HD) + col] = f2bf(oA[dj][r] * iA);
      out[(size_t)rowB * (NH * HD) + col] = f2bf(oB[dj][r] * iB);
    }
  }
}

// ---------------------------------------------------------------------------
extern "C" void kernel_launch(void* const* d_in, const int* in_sizes, int n_in,
                              void* d_out, int out_size, void* d_ws, size_t ws_size,
                              hipStream_t stream)
{
  const float* hidden = (const float*)d_in[0];
  // d_in[1] = attention_mask: structurally known (causal + R visible), unused.
  const float* cosT = (const float*)d_in[2];
  const float* sinT = (const float*)d_in[3];
  const float* vk   = (const float*)d_in[4];
  const float* vv   = (const float*)d_in[5];
  const float* Wq   = (const float*)d_in[6];
  const float* Wk   = (const float*)d_in[7];
  const float* Wv   = (const float*)d_in[8];
  const float* Wo   = (const float*)d_in[9];
  const float* qnw  = (const float*)d_in[10];
  const float* knw  = (const float*)d_in[11];
  const float* alog = (const float*)d_in[12];

  char* ws = (char*)d_ws;
  float* q_projf = (float*)ws;                         // 33,554,432 B
  float* k_projf = (float*)(ws + 33554432);            //  8,388,608 B
  short* Vt      = (short*)(ws + 41943040);            //  4,456,448 B
  short* Qr      = (short*)(ws + 46399488);            // 16,777,216 B
  short* Kr      = (short*)(ws + 63176704);            //  4,456,448 B
  short* Xb      = (short*)(ws + 67633152);            // 16,777,216 B
  short* Wall    = (short*)(ws + 84410368);            // 50,331,648 B  (Wq|Wk|Wv)^T
  short* Wot     = Wall;                               // reused after QKV gemm
  short* attn_out = (short*)ws;                        // reuses q_projf (bf16)
  float* outp = (float*)d_out;

  const float qscale = 0.08838834764831845f;           // 128^-0.5

  dim3 blk(256);
  convert_x<<<dim3(T_SEQ * DMODEL / 8 / 256), blk, 0, stream>>>(hidden, Xb);
  transpose_convert<<<dim3(64, 64), blk, 0, stream>>>(Wq, Wall, DMODEL, 4096);
  transpose_convert<<<dim3(16, 64), blk, 0, stream>>>(Wk, Wall + (size_t)4096 * DMODEL, DMODEL, 1024);
  transpose_convert<<<dim3(16, 64), blk, 0, stream>>>(Wv, Wall + (size_t)5120 * DMODEL, DMODEL, 1024);
  gemm128<3><<<dim3(48, 16), blk, 0, stream>>>(Xb, Wall, q_projf, k_projf, Vt, T_SEQ, 6144, DMODEL);
  rope_kernel<<<dim3(T_SEQ * NH / 4),  blk, 0, stream>>>(q_projf, qnw, cosT, sinT, Qr, 5, T_SEQ, 0, qscale);
  rope_kernel<<<dim3(T_SEQ * NKV / 4), blk, 0, stream>>>(k_projf, knw, cosT, sinT, Kr, 3, TKV, RVIRT, 1.0f);
  inject_kernel<<<dim3(NKV * RVIRT * HD / 256), blk, 0, stream>>>(vk, vv, alog, Kr, Vt);
  attn_kernel<<<dim3(16, NH), blk, 0, stream>>>(Qr, Kr, Vt, attn_out);
  transpose_convert<<<dim3(64, 64), blk, 0, stream>>>(Wo, Wot, 4096, 4096);
  gemm128<0><<<dim3(32, 16), blk, 0, stream>>>(attn_out, Wot, outp, nullptr, nullptr, T_SEQ, 4096, 4096);
}

// Round 4
// 478.800 us; speedup vs baseline: 1.1056x; 1.1056x over previous
//
#include <hip/hip_runtime.h>
#include <hip/hip_bf16.h>

#define T_SEQ 2048
#define DMODEL 4096
#define NH 32
#define NKV 8
#define HD 128
#define RVIRT 128
#define TKV (RVIRT + T_SEQ)   // 2176

typedef __attribute__((ext_vector_type(8))) short s16x8;
typedef __attribute__((ext_vector_type(4))) short s16x4;
typedef __attribute__((ext_vector_type(4))) float f32x4;
typedef __attribute__((ext_vector_type(4))) float float4v;

static __device__ __forceinline__ short f2bf(float f) {
  union { __hip_bfloat16 h; short s; } u; u.h = __float2bfloat16(f); return u.s;
}

static __device__ __forceinline__ void gload16(const void* g, void* l) {
  __builtin_amdgcn_global_load_lds(
      (const __attribute__((address_space(1))) void*)g,
      (__attribute__((address_space(3))) void*)l, 16, 0, 0);
}

// ---------------------------------------------------------------------------
// fp32 -> bf16 convert (X). Each thread converts 8 elements.
// ---------------------------------------------------------------------------
__global__ __launch_bounds__(256) void convert_x(const float* __restrict__ src,
                                                 short* __restrict__ dst)
{
  int i = (blockIdx.x * 256 + threadIdx.x) * 8;
  float4v a = *(const float4v*)(src + i);
  float4v b = *(const float4v*)(src + i + 4);
  s16x8 o;
#pragma unroll
  for (int j = 0; j < 4; ++j) { o[j] = f2bf(a[j]); o[4 + j] = f2bf(b[j]); }
  *(s16x8*)(dst + i) = o;
}

// ---------------------------------------------------------------------------
// Transpose + convert: src [K][N] fp32 -> dst [N][K] bf16. 64x64 tiles.
// ---------------------------------------------------------------------------
__global__ __launch_bounds__(256) void transpose_convert(const float* __restrict__ src,
    short* __restrict__ dst, int K, int N)
{
  __shared__ float tile[64][65];
  const int k0 = blockIdx.y * 64, n0 = blockIdx.x * 64;
  const int tid = threadIdx.x;
  const int rr = tid >> 4, c4 = (tid & 15) * 4;
#pragma unroll
  for (int it = 0; it < 4; ++it) {
    int row = it * 16 + rr;
    float4v v = *(const float4v*)(src + (size_t)(k0 + row) * N + n0 + c4);
    tile[row][c4] = v[0]; tile[row][c4 + 1] = v[1];
    tile[row][c4 + 2] = v[2]; tile[row][c4 + 3] = v[3];
  }
  __syncthreads();
  const int n = tid >> 3, seg = tid & 7;
#pragma unroll
  for (int it = 0; it < 2; ++it) {
    int nn = it * 32 + n;
    s16x8 o;
#pragma unroll
    for (int j = 0; j < 8; ++j) o[j] = f2bf(tile[seg * 8 + j][nn]);
    *(s16x8*)(dst + (size_t)(n0 + nn) * K + k0 + seg * 8) = o;
  }
}

// ---------------------------------------------------------------------------
// gemm256q: m201-class 256x256 8-wave 4-phase GEMM. C = A[M][K] x Bt[N][K]^T.
//  - BK=64, 2-buffer LDS (2 x 64 KB = 128 KB). Row-major [256][128B] per
//    operand with XOR swizzle phys(pr,cb) = pr*128 + (cb ^ ((pr&7)<<4)).
//    LDS row pr is a PERMUTATION of tile rows chosen so each staging
//    instruction (64 contiguous pr) covers exactly one phase's read set:
//      A: pr = rh*128 + h*64 + s      (h = row half, rh = quadrant row set)
//      B: pr = ch*128 + b2*64 + b1*32 + (j*16+lo)   (ch = quadrant col set)
//  - Staging: thread t, instr jj: pr = (t>>3)+jj*64, dest = tid*16 + jj*8192
//    (linear, gload_lds-legal); global src column pre-swizzled
//    (((t&7)^((t>>3)&7))*16) so ds_reads with the XOR see logical data.
//    8 lanes per 128B row segment -> fully coalesced.
//  - Phases per K-tile (C-quadrants, operand reuse; 24 ds_read/64 MFMA):
//      ph0: read a(rh0)+b0(ch0), stage A-rh0(t+1), MFMA Q(0,0), vmcnt(4)
//      ph1: read b1(ch1),        stage B-ch0(t+1), MFMA Q(0,1), vmcnt(4)
//      ph2: read a(rh1),         stage B-ch1(t+1), MFMA Q(1,1), no wait
//      ph3: (no reads),          stage A-rh1(t+1), MFMA Q(1,0), vmcnt(4)
//    Each vmcnt(4) guarantees the unit read one barrier later (issued >= 3
//    phases earlier) while leaving the 2 youngest units in flight. Last
//    tile peeled: vmcnt(2)/vmcnt(0).
// ---------------------------------------------------------------------------
template<int EPI>
__global__ __launch_bounds__(512, 2) void gemm256q(const short* __restrict__ Ab,
    const short* __restrict__ Btb, float* __restrict__ C0,
    float* __restrict__ Ck, short* __restrict__ Cv, int M, int N, int K)
{
  __shared__ __align__(16) char lds[2 * 65536];
  const int tid = threadIdx.x, lane = tid & 63, w = tid >> 6;
  const int lo = lane & 15, g = lane >> 4;
  const int wm = w >> 2, wn = w & 3;
  const int m0 = blockIdx.y * 256, n0 = blockIdx.x * 256;
  const int NT = K >> 6;
  const int aswz = (lo & 7) << 4;
  const int bnr = (wn >> 1) * 64 + (wn & 1) * 32;
  const int t8 = tid >> 3, t7 = tid & 7;
  const int swc = ((t7 ^ (t8 & 7)) * 16) >> 1;          // shorts, pre-swizzled col

  const short* As[4]; const short* Bs[4];
#pragma unroll
  for (int jj = 0; jj < 4; ++jj) {
    int pr = t8 + jj * 64;
    int ra = ((pr >> 6) & 1) * 128 + (pr >> 7) * 64 + (pr & 63);
    As[jj] = Ab + (size_t)(m0 + ra) * K + swc;
    int rb = ((pr >> 6) & 1) * 128 + ((pr >> 5) & 1) * 64 + (pr >> 7) * 32 + (pr & 31);
    Bs[jj] = Btb + (size_t)(n0 + rb) * K + swc;
  }

  auto SA = [&](char* nb, int rh, int y) {
#pragma unroll
    for (int u = 0; u < 2; ++u)
      gload16(As[rh * 2 + u] + y * 64, nb + tid * 16 + (rh * 2 + u) * 8192);
  };
  auto SB = [&](char* nb, int ch, int y) {
#pragma unroll
    for (int u = 0; u < 2; ++u)
      gload16(Bs[ch * 2 + u] + y * 64, nb + 32768 + tid * 16 + (ch * 2 + u) * 8192);
  };

  f32x4 acc[8][4];
#pragma unroll
  for (int i = 0; i < 8; ++i)
#pragma unroll
    for (int j = 0; j < 4; ++j) acc[i][j] = (f32x4){0.f, 0.f, 0.f, 0.f};

  s16x8 a[4][2], b0[2][2], b1[2][2];

#define LDA(RH) \
  _Pragma("unroll") for (int i = 0; i < 4; ++i) \
  _Pragma("unroll") for (int kk = 0; kk < 2; ++kk) \
    a[i][kk] = *(const s16x8*)(bu + ((RH) * 128 + wm * 64 + i * 16 + lo) * 128 + ((kk * 64 + g * 16) ^ aswz));
#define LDB(BV, CH) \
  _Pragma("unroll") for (int j = 0; j < 2; ++j) \
  _Pragma("unroll") for (int kk = 0; kk < 2; ++kk) \
    BV[j][kk] = *(const s16x8*)(bu + 32768 + ((CH) * 128 + bnr + j * 16 + lo) * 128 + ((kk * 64 + g * 16) ^ aswz));
#define MMQ(RB, CB, BV) \
  __builtin_amdgcn_s_setprio(1); \
  _Pragma("unroll") for (int i = 0; i < 4; ++i) \
  _Pragma("unroll") for (int j = 0; j < 2; ++j) { \
    f32x4 z = __builtin_amdgcn_mfma_f32_16x16x32_bf16(a[i][0], BV[j][0], acc[(RB) + i][(CB) + j], 0, 0, 0); \
    acc[(RB) + i][(CB) + j] = __builtin_amdgcn_mfma_f32_16x16x32_bf16(a[i][1], BV[j][1], z, 0, 0, 0); \
  } \
  __builtin_amdgcn_s_setprio(0);
#define TOPSYNC() \
  __builtin_amdgcn_s_barrier(); \
  asm volatile("s_waitcnt lgkmcnt(0)" ::: "memory"); \
  __builtin_amdgcn_sched_barrier(0);

  // prologue: tile 0's four units in phase order
  SA(lds, 0, 0); SB(lds, 0, 0); SB(lds, 1, 0); SA(lds, 1, 0);
  asm volatile("s_waitcnt vmcnt(4)" ::: "memory");
  __builtin_amdgcn_s_barrier();

  for (int t = 0; t < NT; ++t) {
    const char* bu = lds + (t & 1) * 65536;
    char* nb = lds + ((t + 1) & 1) * 65536;
    const bool pre = (t + 1 < NT);
    // ---- ph0: Q(0,0)
    LDA(0); LDB(b0, 0);
    if (pre) SA(nb, 0, t + 1);
    TOPSYNC();
    MMQ(0, 0, b0);
    if (pre) asm volatile("s_waitcnt vmcnt(4)" ::: "memory");
    else     asm volatile("s_waitcnt vmcnt(2)" ::: "memory");
    __builtin_amdgcn_s_barrier();
    // ---- ph1: Q(0,1)
    LDB(b1, 1);
    if (pre) SB(nb, 0, t + 1);
    TOPSYNC();
    MMQ(0, 2, b1);
    if (pre) asm volatile("s_waitcnt vmcnt(4)" ::: "memory");
    else     asm volatile("s_waitcnt vmcnt(0)" ::: "memory");
    __builtin_amdgcn_s_barrier();
    // ---- ph2: Q(1,1)
    LDA(1);
    if (pre) SB(nb, 1, t + 1);
    TOPSYNC();
    MMQ(4, 2, b1);
    __builtin_amdgcn_s_barrier();
    // ---- ph3: Q(1,0) (a from ph2, b0 from ph0)
    if (pre) SA(nb, 1, t + 1);
    __builtin_amdgcn_s_barrier();
    MMQ(4, 0, b0);
    if (pre) asm volatile("s_waitcnt vmcnt(4)" ::: "memory");
    __builtin_amdgcn_s_barrier();
  }
#undef LDA
#undef LDB
#undef MMQ
#undef TOPSYNC

#pragma unroll
  for (int i = 0; i < 8; ++i)
#pragma unroll
    for (int j = 0; j < 4; ++j)
#pragma unroll
      for (int r = 0; r < 4; ++r) {
        int row = m0 + wm * 128 + i * 16 + g * 4 + r;
        int col = n0 + wn * 64 + j * 16 + lo;
        float val = acc[i][j][r];
        if (EPI == 0) {
          C0[(size_t)row * N + col] = val;
        } else {
          if (col < 4096) C0[(size_t)row * 4096 + col] = val;
          else if (col < 5120) Ck[(size_t)row * 1024 + (col - 4096)] = val;
          else {
            int vcol = col - 5120;
            Cv[(size_t)((vcol >> 7) * HD + (vcol & 127)) * TKV + RVIRT + row] = f2bf(val);
          }
        }
      }
}

// ---------------------------------------------------------------------------
// RMSNorm + RoPE. One wave per (t, head). qs folds 1/sqrt(HD) into Q.
// ---------------------------------------------------------------------------
__global__ __launch_bounds__(256) void rope_kernel(const float* __restrict__ proj,
    const float* __restrict__ nw, const float* __restrict__ cosT,
    const float* __restrict__ sinT, short* __restrict__ out,
    int nh_shift, int rows_total, int row0, float qs)
{
  int wid = blockIdx.x * 4 + (threadIdx.x >> 6);
  int lane = threadIdx.x & 63;
  int nh = 1 << nh_shift;
  int t = wid >> nh_shift;
  int hh = wid & (nh - 1);
  const float* src = proj + (size_t)t * (nh * HD) + hh * HD;
  float x1 = src[lane];
  float x2 = src[lane + 64];
  float ss = x1 * x1 + x2 * x2;
#pragma unroll
  for (int off = 32; off > 0; off >>= 1) ss += __shfl_xor(ss, off, 64);
  float rms = rsqrtf(ss * (1.0f / 128.0f) + 1e-6f);
  float n1 = x1 * rms * nw[lane];
  float n2 = x2 * rms * nw[lane + 64];
  float c1 = cosT[t * HD + lane], c2 = cosT[t * HD + lane + 64];
  float s1 = sinT[t * HD + lane], s2 = sinT[t * HD + lane + 64];
  short* dst = out + ((size_t)hh * rows_total + row0 + t) * HD;
  dst[lane]      = f2bf((n1 * c1 - n2 * s1) * qs);
  dst[lane + 64] = f2bf((n2 * c2 + n1 * s2) * qs);
}

// ---------------------------------------------------------------------------
// Virtual KV injection.
// ---------------------------------------------------------------------------
__global__ __launch_bounds__(256) void inject_kernel(const float* __restrict__ vk,
    const float* __restrict__ vv, const float* __restrict__ logit,
    short* __restrict__ Kr, short* __restrict__ Vt)
{
  int idx = blockIdx.x * 256 + threadIdx.x;   // < 8*128*128
  float alpha = 0.5f / (1.0f + __expf(-logit[0]));
  int kv = idx >> 14, rem = idx & 16383, r = rem >> 7, d = rem & 127;
  Kr[((size_t)kv * TKV + r) * HD + d] = f2bf(vk[idx] * alpha);
  Vt[((size_t)kv * HD + d) * TKV + r] = f2bf(vv[idx] * alpha);
}

// ---------------------------------------------------------------------------
// Flash attention v4 = r5's staged structure + r6's cheap softmax.
// ---------------------------------------------------------------------------
template<bool MASKED>
static __device__ __forceinline__ void attn_tile(
    const s16x8* qf, float& m, float& l, f32x4* o,
    const char* Ksb, const char* Vsb, char* Psw,
    int kvt, int qr, int lo, int g)
{
  // S^T: sfr[cj][r] = S[k = kvt*64 + cj*16 + g*4 + r][q = lo]
  f32x4 sfr[4];
#pragma unroll
  for (int cj = 0; cj < 4; ++cj) {
    f32x4 z = {};
    const int kr = cj * 16 + lo;
#pragma unroll
    for (int kk = 0; kk < 4; ++kk) {
      s16x8 kf = *(const s16x8*)(Ksb + ((kr * 256 + kk * 64 + g * 16) ^ ((kr & 7) << 4)));
      z = __builtin_amdgcn_mfma_f32_16x16x32_bf16(kf, qf[kk], z, 0, 0, 0);
    }
    sfr[cj] = z;
  }
  float mx = -3.0e38f;
#pragma unroll
  for (int cj = 0; cj < 4; ++cj)
#pragma unroll
    for (int r = 0; r < 4; ++r) {
      float s = sfr[cj][r];
      if (MASKED) {
        int k = kvt * 64 + cj * 16 + g * 4 + r;
        bool ok = (k < RVIRT) || (k - RVIRT <= qr);
        s = ok ? s : -3.0e38f;
        sfr[cj][r] = s;
      }
      mx = fmaxf(mx, s);
    }
  mx = fmaxf(mx, __shfl_xor(mx, 16, 64));
  mx = fmaxf(mx, __shfl_xor(mx, 32, 64));
  if (__any(mx > m + 8.0f)) {           // defer-max
    float mnew = fmaxf(m, mx);
    float fs = __expf(m - mnew);
    m = mnew;
    l *= fs;
#pragma unroll
    for (int r = 0; r < 4; ++r) {
      float fsq = __shfl(fs, g * 4 + r, 64);
#pragma unroll
      for (int dj = 0; dj < 8; ++dj) o[dj][r] *= fsq;
    }
  }
  float rowsum = 0.f;
#pragma unroll
  for (int cj = 0; cj < 4; ++cj) {
    s16x4 pk;
#pragma unroll
    for (int r = 0; r < 4; ++r) {
      float pv = __expf(sfr[cj][r] - m);   // masked lanes: exp(-inf) = 0
      rowsum += pv;
      pk[r] = f2bf(pv);
    }
    *(s16x4*)(Psw + ((lo * 128 + cj * 32 + g * 8) ^ ((lo & 7) << 4))) = pk;
  }
  rowsum += __shfl_xor(rowsum, 16, 64);
  rowsum += __shfl_xor(rowsum, 32, 64);
  l += rowsum;
  // PV: pf (A-layout) from per-wave LDS; vf from Vs LDS
  s16x8 pf[2];
#pragma unroll
  for (int k2 = 0; k2 < 2; ++k2)
    pf[k2] = *(const s16x8*)(Psw + ((lo * 128 + k2 * 64 + g * 16) ^ ((lo & 7) << 4)));
#pragma unroll
  for (int dj = 0; dj < 8; ++dj) {
    const int d = dj * 16 + lo;
    const int vswz = ((d ^ (d >> 3)) & 7) << 4;
#pragma unroll
    for (int k2 = 0; k2 < 2; ++k2) {
      s16x8 vf = *(const s16x8*)(Vsb + ((d * 128 + k2 * 64 + g * 16) ^ vswz));
      o[dj] = __builtin_amdgcn_mfma_f32_16x16x32_bf16(pf[k2], vf, o[dj], 0, 0, 0);
    }
  }
}

__global__ __launch_bounds__(256) void attn_kernel(const short* __restrict__ Qr,
    const short* __restrict__ Kr, const short* __restrict__ Vt,
    short* __restrict__ out)
{
  __shared__ short Ks[64 * 128];                // (r*256 + c*16) ^ ((r&7)<<4)
  __shared__ short Vs[128 * 64];                // (d*128 + c8*16) ^ (((d^(d>>3))&7)<<4)
  __shared__ __align__(16) char Ps[4 * 4096];   // per wave: 2KB A-set + 2KB B-set
  const int tid = threadIdx.x, lane = tid & 63, w = tid >> 6;
  const int h = blockIdx.y, kvh = h >> 2, bx = blockIdx.x;
  const int lo = lane & 15, g = lane >> 4;
  const int q0A = bx * 64, q0B = (31 - bx) * 64;
  char* PsA = Ps + w * 4096;
  char* PsB = PsA + 2048;
  const short* Kb = Kr + (size_t)kvh * TKV * HD;
  const short* Vb = Vt + (size_t)kvh * HD * TKV;

  s16x8 qfA[4], qfB[4];
#pragma unroll
  for (int kk = 0; kk < 4; ++kk) {
    qfA[kk] = *(const s16x8*)(Qr + ((size_t)h * T_SEQ + q0A + w * 16 + lo) * HD + kk * 32 + g * 8);
    qfB[kk] = *(const s16x8*)(Qr + ((size_t)h * T_SEQ + q0B + w * 16 + lo) * HD + kk * 32 + g * 8);
  }

  float mA = -3.0e38f, lA = 0.f, mB = -3.0e38f, lB = 0.f;
  f32x4 oA[8] = {}, oB[8] = {};
  const int ntA = bx + 3, ntB = 34 - bx;
  const int qrA = q0A + w * 16 + lo, qrB = q0B + w * 16 + lo;

  s16x8 kst[4], vst[4];
  auto ISSUE = [&](int kvt) {
#pragma unroll
    for (int p = 0; p < 4; ++p) {
      int ci = p * 256 + tid;
      kst[p] = *(const s16x8*)(Kb + (size_t)(kvt * 64 + (ci >> 4)) * HD + (ci & 15) * 8);
      vst[p] = *(const s16x8*)(Vb + (size_t)(ci >> 3) * TKV + kvt * 64 + (ci & 7) * 8);
    }
  };
  auto WRITE = [&]() {
#pragma unroll
    for (int p = 0; p < 4; ++p) {
      int ci = p * 256 + tid;
      int r = ci >> 4, c = ci & 15;
      *(s16x8*)((char*)Ks + ((r * 256 + c * 16) ^ ((r & 7) << 4))) = kst[p];
      int d = ci >> 3, c8 = ci & 7;
      *(s16x8*)((char*)Vs + ((d * 128 + c8 * 16) ^ (((d ^ (d >> 3)) & 7) << 4))) = vst[p];
    }
  };

  ISSUE(0);
  WRITE();
  __syncthreads();

  for (int kvt = 0; kvt < ntB; ++kvt) {
    if (kvt + 1 < ntB) ISSUE(kvt + 1);      // loads fly during compute
    if (kvt < ntA) {
      if (kvt == ntA - 1) attn_tile<true >(qfA, mA, lA, oA, (const char*)Ks, (const char*)Vs, PsA, kvt, qrA, lo, g);
      else                attn_tile<false>(qfA, mA, lA, oA, (const char*)Ks, (const char*)Vs, PsA, kvt, qrA, lo, g);
    }
    if (kvt == ntB - 1)   attn_tile<true >(qfB, mB, lB, oB, (const char*)Ks, (const char*)Vs, PsB, kvt, qrB, lo, g);
    else                  attn_tile<false>(qfB, mB, lB, oB, (const char*)Ks, (const char*)Vs, PsB, kvt, qrB, lo, g);
    __syncthreads();                         // all waves done reading tile kvt
    if (kvt + 1 < ntB) WRITE();              // waits vmcnt via reg dependence
    __syncthreads();                         // writes visible
  }
  // epilogue: o row q = g*4 + r; l lives on lane with lo == q (any g)
#pragma unroll
  for (int r = 0; r < 4; ++r) {
    float lqA = __shfl(lA, g * 4 + r, 64);
    float lqB = __shfl(lB, g * 4 + r, 64);
    float iA = 1.f / lqA, iB = 1.f / lqB;
#pragma unroll
    for (int dj = 0; dj < 8; ++dj) {
      int col = h * HD + dj * 16 + lo;
      int rowA = q0A + w * 16 + g * 4 + r;
      int rowB = q0B + w * 16 + g * 4 + r;
      out[(size_t)rowA * (NH * HD) + col] = f2bf(oA[dj][r] * iA);
      out[(size_t)rowB * (NH * HD) + col] = f2bf(oB[dj][r] * iB);
    }
  }
}

// ---------------------------------------------------------------------------
extern "C" void kernel_launch(void* const* d_in, const int* in_sizes, int n_in,
                              void* d_out, int out_size, void* d_ws, size_t ws_size,
                              hipStream_t stream)
{
  const float* hidden = (const float*)d_in[0];
  // d_in[1] = attention_mask: structurally known (causal + R visible), unused.
  const float* cosT = (const float*)d_in[2];
  const float* sinT = (const float*)d_in[3];
  const float* vk   = (const float*)d_in[4];
  const float* vv   = (const float*)d_in[5];
  const float* Wq   = (const float*)d_in[6];
  const float* Wk   = (const float*)d_in[7];
  const float* Wv   = (const float*)d_in[8];
  const float* Wo   = (const float*)d_in[9];
  const float* qnw  = (const float*)d_in[10];
  const float* knw  = (const float*)d_in[11];
  const float* alog = (const float*)d_in[12];

  char* ws = (char*)d_ws;
  float* q_projf = (float*)ws;                         // 33,554,432 B
  float* k_projf = (float*)(ws + 33554432);            //  8,388,608 B
  short* Vt      = (short*)(ws + 41943040);            //  4,456,448 B
  short* Qr      = (short*)(ws + 46399488);            // 16,777,216 B
  short* Kr      = (short*)(ws + 63176704);            //  4,456,448 B
  short* Xb      = (short*)(ws + 67633152);            // 16,777,216 B
  short* Wall    = (short*)(ws + 84410368);            // 50,331,648 B  (Wq|Wk|Wv)^T
  short* Wot     = Wall;                               // reused after QKV gemm
  short* attn_out = (short*)ws;                        // reuses q_projf (bf16)
  float* outp = (float*)d_out;

  const float qscale = 0.08838834764831845f;           // 128^-0.5

  dim3 blk(256);
  convert_x<<<dim3(T_SEQ * DMODEL / 8 / 256), blk, 0, stream>>>(hidden, Xb);
  transpose_convert<<<dim3(64, 64), blk, 0, stream>>>(Wq, Wall, DMODEL, 4096);
  transpose_convert<<<dim3(16, 64), blk, 0, stream>>>(Wk, Wall + (size_t)4096 * DMODEL, DMODEL, 1024);
  transpose_convert<<<dim3(16, 64), blk, 0, stream>>>(Wv, Wall + (size_t)5120 * DMODEL, DMODEL, 1024);
  gemm256q<3><<<dim3(24, 8), dim3(512), 0, stream>>>(Xb, Wall, q_projf, k_projf, Vt, T_SEQ, 6144, DMODEL);
  rope_kernel<<<dim3(T_SEQ * NH / 4),  blk, 0, stream>>>(q_projf, qnw, cosT, sinT, Qr, 5, T_SEQ, 0, qscale);
  rope_kernel<<<dim3(T_SEQ * NKV / 4), blk, 0, stream>>>(k_projf, knw, cosT, sinT, Kr, 3, TKV, RVIRT, 1.0f);
  inject_kernel<<<dim3(NKV * RVIRT * HD / 256), blk, 0, stream>>>(vk, vv, alog, Kr, Vt);
  attn_kernel<<<dim3(16, NH), blk, 0, stream>>>(Qr, Kr, Vt, attn_out);
  transpose_convert<<<dim3(64, 64), blk, 0, stream>>>(Wo, Wot, 4096, 4096);
  gemm256q<0><<<dim3(16, 8), dim3(512), 0, stream>>>(attn_out, Wot, outp, nullptr, nullptr, T_SEQ, 4096, 4096);
}

// Round 5
// 409.626 us; speedup vs baseline: 1.2923x; 1.1689x over previous
//
#include <hip/hip_runtime.h>
#include <hip/hip_bf16.h>

#define T_SEQ 2048
#define DMODEL 4096
#define NH 32
#define NKV 8
#define HD 128
#define RVIRT 128
#define TKV (RVIRT + T_SEQ)   // 2176

typedef __attribute__((ext_vector_type(8))) short s16x8;
typedef __attribute__((ext_vector_type(4))) short s16x4;
typedef __attribute__((ext_vector_type(4))) float f32x4;
typedef __attribute__((ext_vector_type(4))) float float4v;

static __device__ __forceinline__ short f2bf(float f) {
  union { __hip_bfloat16 h; short s; } u; u.h = __float2bfloat16(f); return u.s;
}

static __device__ __forceinline__ void gload16(const void* g, void* l) {
  __builtin_amdgcn_global_load_lds(
      (const __attribute__((address_space(1))) void*)g,
      (__attribute__((address_space(3))) void*)l, 16, 0, 0);
}

#define TOPSYNC() \
  __builtin_amdgcn_s_barrier(); \
  asm volatile("s_waitcnt lgkmcnt(0)" ::: "memory"); \
  __builtin_amdgcn_sched_barrier(0);

// ---------------------------------------------------------------------------
// fp32 -> bf16 convert (X). Each thread converts 8 elements.
// ---------------------------------------------------------------------------
__global__ __launch_bounds__(256) void convert_x(const float* __restrict__ src,
                                                 short* __restrict__ dst)
{
  int i = (blockIdx.x * 256 + threadIdx.x) * 8;
  float4v a = *(const float4v*)(src + i);
  float4v b = *(const float4v*)(src + i + 4);
  s16x8 o;
#pragma unroll
  for (int j = 0; j < 4; ++j) { o[j] = f2bf(a[j]); o[4 + j] = f2bf(b[j]); }
  *(s16x8*)(dst + i) = o;
}

// ---------------------------------------------------------------------------
// Transpose + convert: src [K][N] fp32 -> dst [N][K] bf16. 64x64 tiles.
// ---------------------------------------------------------------------------
__global__ __launch_bounds__(256) void transpose_convert(const float* __restrict__ src,
    short* __restrict__ dst, int K, int N)
{
  __shared__ float tile[64][65];
  const int k0 = blockIdx.y * 64, n0 = blockIdx.x * 64;
  const int tid = threadIdx.x;
  const int rr = tid >> 4, c4 = (tid & 15) * 4;
#pragma unroll
  for (int it = 0; it < 4; ++it) {
    int row = it * 16 + rr;
    float4v v = *(const float4v*)(src + (size_t)(k0 + row) * N + n0 + c4);
    tile[row][c4] = v[0]; tile[row][c4 + 1] = v[1];
    tile[row][c4 + 2] = v[2]; tile[row][c4 + 3] = v[3];
  }
  __syncthreads();
  const int n = tid >> 3, seg = tid & 7;
#pragma unroll
  for (int it = 0; it < 2; ++it) {
    int nn = it * 32 + n;
    s16x8 o;
#pragma unroll
    for (int j = 0; j < 8; ++j) o[j] = f2bf(tile[seg * 8 + j][nn]);
    *(s16x8*)(dst + (size_t)(n0 + nn) * K + k0 + seg * 8) = o;
  }
}

// ---------------------------------------------------------------------------
// gemm_qkv: 256x192 tile, 8 waves (4M x 2N), BK=64, 3 phases/K-tile.
// Grid 8x32 = 256 blocks = 100% CU fill (the r4 kernel's 875 TF active-CU
// throughput was capped by 75% fill; this keeps the schedule family).
//  - LDS slot 56KB (A 256x128B identity-perm + B 192x128B phase-perm), dbuf.
//  - B perm: pr = p*64 + wn*32 + e*16 + s  <->  row = wn*96 + (2p+e)*16 + s
//    so each 64-row unit (1 gload16/thread) is exactly phase p's read set.
//  - Phases: ph0{LDA all + LDB(0); stage A0,A1,A2(t+1); 16 MFMA; vmcnt(4)}
//            ph1{LDB(1); stage A3,B0(t+1); 16 MFMA; vmcnt(5)}
//            ph2{LDB(2); stage B1,B2(t+1); 16 MFMA; vmcnt(2)}
//    waits guard the NEXT phase's units; every unit has >=2 phases in
//    flight before its wait. Tail tile: 1/0/none.
// ---------------------------------------------------------------------------
__global__ __launch_bounds__(512, 2) void gemm_qkv(const short* __restrict__ Ab,
    const short* __restrict__ Btb, float* __restrict__ C0,
    float* __restrict__ Ck, short* __restrict__ Cv, int K)
{
  constexpr int SLOT = 57344;           // 32KB A + 24KB B
  __shared__ __align__(16) char lds[2 * SLOT];
  const int tid = threadIdx.x, lane = tid & 63, w = tid >> 6;
  const int lo = lane & 15, g = lane >> 4;
  const int wm = w >> 1, wn = w & 1;    // 4M x 2N
  const int m0 = blockIdx.y * 256, n0 = blockIdx.x * 192;
  const int NT = K >> 6;
  const int aswz = (lo & 7) << 4;
  const int t8 = tid >> 3, t7 = tid & 7;
  const int swc = (t7 ^ (t8 & 7)) * 8;  // shorts, pre-swizzled col

  const short* As = Ab + (size_t)(m0 + t8) * K + swc;
  const short* Bs[3];
#pragma unroll
  for (int jj = 0; jj < 3; ++jj) {
    int row = (t8 >> 5) * 96 + (2 * jj + ((t8 >> 4) & 1)) * 16 + (t8 & 15);
    Bs[jj] = Btb + (size_t)(n0 + row) * K + swc;
  }
  auto SA = [&](char* nb, int jj, int y) {
    gload16(As + (size_t)jj * 64 * K + y * 64, nb + tid * 16 + jj * 8192);
  };
  auto SB = [&](char* nb, int jj, int y) {
    gload16(Bs[jj] + y * 64, nb + 32768 + tid * 16 + jj * 8192);
  };

  f32x4 acc[4][6];
#pragma unroll
  for (int i = 0; i < 4; ++i)
#pragma unroll
    for (int j = 0; j < 6; ++j) acc[i][j] = (f32x4){0.f, 0.f, 0.f, 0.f};

  s16x8 a[4][2], bq[2][2];

#define QLDB(P) \
  _Pragma("unroll") for (int jj = 0; jj < 2; ++jj) \
  _Pragma("unroll") for (int kk = 0; kk < 2; ++kk) \
    bq[jj][kk] = *(const s16x8*)(bu + 32768 + ((P) * 64 + wn * 32 + jj * 16 + lo) * 128 + ((kk * 64 + g * 16) ^ aswz));
#define QMMQ(P) \
  __builtin_amdgcn_s_setprio(1); \
  _Pragma("unroll") for (int i = 0; i < 4; ++i) \
  _Pragma("unroll") for (int jj = 0; jj < 2; ++jj) { \
    f32x4 z = __builtin_amdgcn_mfma_f32_16x16x32_bf16(a[i][0], bq[jj][0], acc[i][(P) * 2 + jj], 0, 0, 0); \
    acc[i][(P) * 2 + jj] = __builtin_amdgcn_mfma_f32_16x16x32_bf16(a[i][1], bq[jj][1], z, 0, 0, 0); \
  } \
  __builtin_amdgcn_s_setprio(0);

  // prologue: tile 0 fully staged
  SA(lds, 0, 0); SA(lds, 1, 0); SA(lds, 2, 0); SA(lds, 3, 0);
  SB(lds, 0, 0); SB(lds, 1, 0); SB(lds, 2, 0);
  asm volatile("s_waitcnt vmcnt(0)" ::: "memory");
  __builtin_amdgcn_s_barrier();

  for (int t = 0; t < NT; ++t) {
    const char* bu = lds + (t & 1) * SLOT;
    char* nb = lds + ((t + 1) & 1) * SLOT;
    const bool pre = (t + 1 < NT);
    // ---- ph0: cols 0,1
#pragma unroll
    for (int i = 0; i < 4; ++i)
#pragma unroll
      for (int kk = 0; kk < 2; ++kk)
        a[i][kk] = *(const s16x8*)(bu + (wm * 64 + i * 16 + lo) * 128 + ((kk * 64 + g * 16) ^ aswz));
    QLDB(0);
    if (pre) { SA(nb, 0, t + 1); SA(nb, 1, t + 1); SA(nb, 2, t + 1); }
    TOPSYNC();
    QMMQ(0);
    if (pre) asm volatile("s_waitcnt vmcnt(4)" ::: "memory");
    else     asm volatile("s_waitcnt vmcnt(1)" ::: "memory");
    __builtin_amdgcn_s_barrier();
    // ---- ph1: cols 2,3
    QLDB(1);
    if (pre) { SA(nb, 3, t + 1); SB(nb, 0, t + 1); }
    TOPSYNC();
    QMMQ(1);
    if (pre) asm volatile("s_waitcnt vmcnt(5)" ::: "memory");
    else     asm volatile("s_waitcnt vmcnt(0)" ::: "memory");
    __builtin_amdgcn_s_barrier();
    // ---- ph2: cols 4,5
    QLDB(2);
    if (pre) { SB(nb, 1, t + 1); SB(nb, 2, t + 1); }
    TOPSYNC();
    QMMQ(2);
    if (pre) asm volatile("s_waitcnt vmcnt(2)" ::: "memory");
    __builtin_amdgcn_s_barrier();
  }
#undef QLDB
#undef QMMQ

#pragma unroll
  for (int i = 0; i < 4; ++i)
#pragma unroll
    for (int j = 0; j < 6; ++j)
#pragma unroll
      for (int r = 0; r < 4; ++r) {
        int row = m0 + wm * 64 + i * 16 + g * 4 + r;
        int col = n0 + wn * 96 + j * 16 + lo;
        float val = acc[i][j][r];
        if (col < 4096) C0[(size_t)row * 4096 + col] = val;
        else if (col < 5120) Ck[(size_t)row * 1024 + (col - 4096)] = val;
        else {
          int vcol = col - 5120;
          Cv[(size_t)((vcol >> 7) * HD + (vcol & 127)) * TKV + RVIRT + row] = f2bf(val);
        }
      }
}

// ---------------------------------------------------------------------------
// gemm_out: 128x256 tile, 8 waves (2M x 4N), BK=64, 2 phases/K-tile.
// Grid 16x16 = 256 blocks = 100% fill (was 128 blocks = 50%).
//  - LDS slot 48KB (A 128x128B identity + B 256x128B phase-perm), dbuf.
//  - B perm: pr = j*64 + wn*16 + s  <->  row = wn*64 + j*16 + s.
//  - ph0{LDA all + LDB(0,1); stage A0,A1,B0,B1(t+1); 16 MFMA; vmcnt(4)}
//    ph1{LDB(2,3);           stage B2,B3(t+1);       16 MFMA; vmcnt(2)}
//    Tail tile: 0/none.
// ---------------------------------------------------------------------------
__global__ __launch_bounds__(512, 2) void gemm_out(const short* __restrict__ Ab,
    const short* __restrict__ Btb, float* __restrict__ C0, int K)
{
  constexpr int SLOT = 49152;           // 16KB A + 32KB B
  __shared__ __align__(16) char lds[2 * SLOT];
  const int tid = threadIdx.x, lane = tid & 63, w = tid >> 6;
  const int lo = lane & 15, g = lane >> 4;
  const int wm = w >> 2, wn = w & 3;    // 2M x 4N
  const int m0 = blockIdx.y * 128, n0 = blockIdx.x * 256;
  const int NT = K >> 6;
  const int aswz = (lo & 7) << 4;
  const int t8 = tid >> 3, t7 = tid & 7;
  const int swc = (t7 ^ (t8 & 7)) * 8;  // shorts

  const short* As = Ab + (size_t)(m0 + t8) * K + swc;
  const short* Bs[4];
#pragma unroll
  for (int jj = 0; jj < 4; ++jj) {
    int row = (t8 >> 4) * 64 + jj * 16 + (t8 & 15);
    Bs[jj] = Btb + (size_t)(n0 + row) * K + swc;
  }
  auto SA = [&](char* nb, int jj, int y) {
    gload16(As + (size_t)jj * 64 * K + y * 64, nb + tid * 16 + jj * 8192);
  };
  auto SB = [&](char* nb, int jj, int y) {
    gload16(Bs[jj] + y * 64, nb + 16384 + tid * 16 + jj * 8192);
  };

  f32x4 acc[4][4];
#pragma unroll
  for (int i = 0; i < 4; ++i)
#pragma unroll
    for (int j = 0; j < 4; ++j) acc[i][j] = (f32x4){0.f, 0.f, 0.f, 0.f};

  s16x8 a[4][2], bq[2][2];

#define OLDB(P) \
  _Pragma("unroll") for (int jj = 0; jj < 2; ++jj) \
  _Pragma("unroll") for (int kk = 0; kk < 2; ++kk) \
    bq[jj][kk] = *(const s16x8*)(bu + 16384 + (((P) * 2 + jj) * 64 + wn * 16 + lo) * 128 + ((kk * 64 + g * 16) ^ aswz));
#define OMMQ(P) \
  __builtin_amdgcn_s_setprio(1); \
  _Pragma("unroll") for (int i = 0; i < 4; ++i) \
  _Pragma("unroll") for (int jj = 0; jj < 2; ++jj) { \
    f32x4 z = __builtin_amdgcn_mfma_f32_16x16x32_bf16(a[i][0], bq[jj][0], acc[i][(P) * 2 + jj], 0, 0, 0); \
    acc[i][(P) * 2 + jj] = __builtin_amdgcn_mfma_f32_16x16x32_bf16(a[i][1], bq[jj][1], z, 0, 0, 0); \
  } \
  __builtin_amdgcn_s_setprio(0);

  SA(lds, 0, 0); SA(lds, 1, 0);
  SB(lds, 0, 0); SB(lds, 1, 0); SB(lds, 2, 0); SB(lds, 3, 0);
  asm volatile("s_waitcnt vmcnt(0)" ::: "memory");
  __builtin_amdgcn_s_barrier();

  for (int t = 0; t < NT; ++t) {
    const char* bu = lds + (t & 1) * SLOT;
    char* nb = lds + ((t + 1) & 1) * SLOT;
    const bool pre = (t + 1 < NT);
    // ---- ph0: cols 0,1
#pragma unroll
    for (int i = 0; i < 4; ++i)
#pragma unroll
      for (int kk = 0; kk < 2; ++kk)
        a[i][kk] = *(const s16x8*)(bu + (wm * 64 + i * 16 + lo) * 128 + ((kk * 64 + g * 16) ^ aswz));
    OLDB(0);
    if (pre) { SA(nb, 0, t + 1); SA(nb, 1, t + 1); SB(nb, 0, t + 1); SB(nb, 1, t + 1); }
    TOPSYNC();
    OMMQ(0);
    if (pre) asm volatile("s_waitcnt vmcnt(4)" ::: "memory");
    else     asm volatile("s_waitcnt vmcnt(0)" ::: "memory");
    __builtin_amdgcn_s_barrier();
    // ---- ph1: cols 2,3
    OLDB(1);
    if (pre) { SB(nb, 2, t + 1); SB(nb, 3, t + 1); }
    TOPSYNC();
    OMMQ(1);
    if (pre) asm volatile("s_waitcnt vmcnt(2)" ::: "memory");
    __builtin_amdgcn_s_barrier();
  }
#undef OLDB
#undef OMMQ

#pragma unroll
  for (int i = 0; i < 4; ++i)
#pragma unroll
    for (int j = 0; j < 4; ++j)
#pragma unroll
      for (int r = 0; r < 4; ++r) {
        int row = m0 + wm * 64 + i * 16 + g * 4 + r;
        int col = n0 + wn * 64 + j * 16 + lo;
        C0[(size_t)row * 4096 + col] = acc[i][j][r];
      }
}

// ---------------------------------------------------------------------------
// RMSNorm + RoPE. One wave per (t, head). qs folds 1/sqrt(HD) into Q.
// ---------------------------------------------------------------------------
__global__ __launch_bounds__(256) void rope_kernel(const float* __restrict__ proj,
    const float* __restrict__ nw, const float* __restrict__ cosT,
    const float* __restrict__ sinT, short* __restrict__ out,
    int nh_shift, int rows_total, int row0, float qs)
{
  int wid = blockIdx.x * 4 + (threadIdx.x >> 6);
  int lane = threadIdx.x & 63;
  int nh = 1 << nh_shift;
  int t = wid >> nh_shift;
  int hh = wid & (nh - 1);
  const float* src = proj + (size_t)t * (nh * HD) + hh * HD;
  float x1 = src[lane];
  float x2 = src[lane + 64];
  float ss = x1 * x1 + x2 * x2;
#pragma unroll
  for (int off = 32; off > 0; off >>= 1) ss += __shfl_xor(ss, off, 64);
  float rms = rsqrtf(ss * (1.0f / 128.0f) + 1e-6f);
  float n1 = x1 * rms * nw[lane];
  float n2 = x2 * rms * nw[lane + 64];
  float c1 = cosT[t * HD + lane], c2 = cosT[t * HD + lane + 64];
  float s1 = sinT[t * HD + lane], s2 = sinT[t * HD + lane + 64];
  short* dst = out + ((size_t)hh * rows_total + row0 + t) * HD;
  dst[lane]      = f2bf((n1 * c1 - n2 * s1) * qs);
  dst[lane + 64] = f2bf((n2 * c2 + n1 * s2) * qs);
}

// ---------------------------------------------------------------------------
// Virtual KV injection.
// ---------------------------------------------------------------------------
__global__ __launch_bounds__(256) void inject_kernel(const float* __restrict__ vk,
    const float* __restrict__ vv, const float* __restrict__ logit,
    short* __restrict__ Kr, short* __restrict__ Vt)
{
  int idx = blockIdx.x * 256 + threadIdx.x;   // < 8*128*128
  float alpha = 0.5f / (1.0f + __expf(-logit[0]));
  int kv = idx >> 14, rem = idx & 16383, r = rem >> 7, d = rem & 127;
  Kr[((size_t)kv * TKV + r) * HD + d] = f2bf(vk[idx] * alpha);
  Vt[((size_t)kv * HD + d) * TKV + r] = f2bf(vv[idx] * alpha);
}

// ---------------------------------------------------------------------------
// Flash attention v4 = r5's staged structure + r6's cheap softmax.
// ---------------------------------------------------------------------------
template<bool MASKED>
static __device__ __forceinline__ void attn_tile(
    const s16x8* qf, float& m, float& l, f32x4* o,
    const char* Ksb, const char* Vsb, char* Psw,
    int kvt, int qr, int lo, int g)
{
  // S^T: sfr[cj][r] = S[k = kvt*64 + cj*16 + g*4 + r][q = lo]
  f32x4 sfr[4];
#pragma unroll
  for (int cj = 0; cj < 4; ++cj) {
    f32x4 z = {};
    const int kr = cj * 16 + lo;
#pragma unroll
    for (int kk = 0; kk < 4; ++kk) {
      s16x8 kf = *(const s16x8*)(Ksb + ((kr * 256 + kk * 64 + g * 16) ^ ((kr & 7) << 4)));
      z = __builtin_amdgcn_mfma_f32_16x16x32_bf16(kf, qf[kk], z, 0, 0, 0);
    }
    sfr[cj] = z;
  }
  float mx = -3.0e38f;
#pragma unroll
  for (int cj = 0; cj < 4; ++cj)
#pragma unroll
    for (int r = 0; r < 4; ++r) {
      float s = sfr[cj][r];
      if (MASKED) {
        int k = kvt * 64 + cj * 16 + g * 4 + r;
        bool ok = (k < RVIRT) || (k - RVIRT <= qr);
        s = ok ? s : -3.0e38f;
        sfr[cj][r] = s;
      }
      mx = fmaxf(mx, s);
    }
  mx = fmaxf(mx, __shfl_xor(mx, 16, 64));
  mx = fmaxf(mx, __shfl_xor(mx, 32, 64));
  if (__any(mx > m + 8.0f)) {           // defer-max
    float mnew = fmaxf(m, mx);
    float fs = __expf(m - mnew);
    m = mnew;
    l *= fs;
#pragma unroll
    for (int r = 0; r < 4; ++r) {
      float fsq = __shfl(fs, g * 4 + r, 64);
#pragma unroll
      for (int dj = 0; dj < 8; ++dj) o[dj][r] *= fsq;
    }
  }
  float rowsum = 0.f;
#pragma unroll
  for (int cj = 0; cj < 4; ++cj) {
    s16x4 pk;
#pragma unroll
    for (int r = 0; r < 4; ++r) {
      float pv = __expf(sfr[cj][r] - m);   // masked lanes: exp(-inf) = 0
      rowsum += pv;
      pk[r] = f2bf(pv);
    }
    *(s16x4*)(Psw + ((lo * 128 + cj * 32 + g * 8) ^ ((lo & 7) << 4))) = pk;
  }
  rowsum += __shfl_xor(rowsum, 16, 64);
  rowsum += __shfl_xor(rowsum, 32, 64);
  l += rowsum;
  // PV: pf (A-layout) from per-wave LDS; vf from Vs LDS
  s16x8 pf[2];
#pragma unroll
  for (int k2 = 0; k2 < 2; ++k2)
    pf[k2] = *(const s16x8*)(Psw + ((lo * 128 + k2 * 64 + g * 16) ^ ((lo & 7) << 4)));
#pragma unroll
  for (int dj = 0; dj < 8; ++dj) {
    const int d = dj * 16 + lo;
    const int vswz = ((d ^ (d >> 3)) & 7) << 4;
#pragma unroll
    for (int k2 = 0; k2 < 2; ++k2) {
      s16x8 vf = *(const s16x8*)(Vsb + ((d * 128 + k2 * 64 + g * 16) ^ vswz));
      o[dj] = __builtin_amdgcn_mfma_f32_16x16x32_bf16(pf[k2], vf, o[dj], 0, 0, 0);
    }
  }
}

__global__ __launch_bounds__(256) void attn_kernel(const short* __restrict__ Qr,
    const short* __restrict__ Kr, const short* __restrict__ Vt,
    short* __restrict__ out)
{
  __shared__ short Ks[64 * 128];                // (r*256 + c*16) ^ ((r&7)<<4)
  __shared__ short Vs[128 * 64];                // (d*128 + c8*16) ^ (((d^(d>>3))&7)<<4)
  __shared__ __align__(16) char Ps[4 * 4096];   // per wave: 2KB A-set + 2KB B-set
  const int tid = threadIdx.x, lane = tid & 63, w = tid >> 6;
  const int h = blockIdx.y, kvh = h >> 2, bx = blockIdx.x;
  const int lo = lane & 15, g = lane >> 4;
  const int q0A = bx * 64, q0B = (31 - bx) * 64;
  char* PsA = Ps + w * 4096;
  char* PsB = PsA + 2048;
  const short* Kb = Kr + (size_t)kvh * TKV * HD;
  const short* Vb = Vt + (size_t)kvh * HD * TKV;

  s16x8 qfA[4], qfB[4];
#pragma unroll
  for (int kk = 0; kk < 4; ++kk) {
    qfA[kk] = *(const s16x8*)(Qr + ((size_t)h * T_SEQ + q0A + w * 16 + lo) * HD + kk * 32 + g * 8);
    qfB[kk] = *(const s16x8*)(Qr + ((size_t)h * T_SEQ + q0B + w * 16 + lo) * HD + kk * 32 + g * 8);
  }

  float mA = -3.0e38f, lA = 0.f, mB = -3.0e38f, lB = 0.f;
  f32x4 oA[8] = {}, oB[8] = {};
  const int ntA = bx + 3, ntB = 34 - bx;
  const int qrA = q0A + w * 16 + lo, qrB = q0B + w * 16 + lo;

  s16x8 kst[4], vst[4];
  auto ISSUE = [&](int kvt) {
#pragma unroll
    for (int p = 0; p < 4; ++p) {
      int ci = p * 256 + tid;
      kst[p] = *(const s16x8*)(Kb + (size_t)(kvt * 64 + (ci >> 4)) * HD + (ci & 15) * 8);
      vst[p] = *(const s16x8*)(Vb + (size_t)(ci >> 3) * TKV + kvt * 64 + (ci & 7) * 8);
    }
  };
  auto WRITE = [&]() {
#pragma unroll
    for (int p = 0; p < 4; ++p) {
      int ci = p * 256 + tid;
      int r = ci >> 4, c = ci & 15;
      *(s16x8*)((char*)Ks + ((r * 256 + c * 16) ^ ((r & 7) << 4))) = kst[p];
      int d = ci >> 3, c8 = ci & 7;
      *(s16x8*)((char*)Vs + ((d * 128 + c8 * 16) ^ (((d ^ (d >> 3)) & 7) << 4))) = vst[p];
    }
  };

  ISSUE(0);
  WRITE();
  __syncthreads();

  for (int kvt = 0; kvt < ntB; ++kvt) {
    if (kvt + 1 < ntB) ISSUE(kvt + 1);      // loads fly during compute
    if (kvt < ntA) {
      if (kvt == ntA - 1) attn_tile<true >(qfA, mA, lA, oA, (const char*)Ks, (const char*)Vs, PsA, kvt, qrA, lo, g);
      else                attn_tile<false>(qfA, mA, lA, oA, (const char*)Ks, (const char*)Vs, PsA, kvt, qrA, lo, g);
    }
    if (kvt == ntB - 1)   attn_tile<true >(qfB, mB, lB, oB, (const char*)Ks, (const char*)Vs, PsB, kvt, qrB, lo, g);
    else                  attn_tile<false>(qfB, mB, lB, oB, (const char*)Ks, (const char*)Vs, PsB, kvt, qrB, lo, g);
    __syncthreads();                         // all waves done reading tile kvt
    if (kvt + 1 < ntB) WRITE();              // waits vmcnt via reg dependence
    __syncthreads();                         // writes visible
  }
  // epilogue: o row q = g*4 + r; l lives on lane with lo == q (any g)
#pragma unroll
  for (int r = 0; r < 4; ++r) {
    float lqA = __shfl(lA, g * 4 + r, 64);
    float lqB = __shfl(lB, g * 4 + r, 64);
    float iA = 1.f / lqA, iB = 1.f / lqB;
#pragma unroll
    for (int dj = 0; dj < 8; ++dj) {
      int col = h * HD + dj * 16 + lo;
      int rowA = q0A + w * 16 + g * 4 + r;
      int rowB = q0B + w * 16 + g * 4 + r;
      out[(size_t)rowA * (NH * HD) + col] = f2bf(oA[dj][r] * iA);
      out[(size_t)rowB * (NH * HD) + col] = f2bf(oB[dj][r] * iB);
    }
  }
}

// ---------------------------------------------------------------------------
extern "C" void kernel_launch(void* const* d_in, const int* in_sizes, int n_in,
                              void* d_out, int out_size, void* d_ws, size_t ws_size,
                              hipStream_t stream)
{
  const float* hidden = (const float*)d_in[0];
  // d_in[1] = attention_mask: structurally known (causal + R visible), unused.
  const float* cosT = (const float*)d_in[2];
  const float* sinT = (const float*)d_in[3];
  const float* vk   = (const float*)d_in[4];
  const float* vv   = (const float*)d_in[5];
  const float* Wq   = (const float*)d_in[6];
  const float* Wk   = (const float*)d_in[7];
  const float* Wv   = (const float*)d_in[8];
  const float* Wo   = (const float*)d_in[9];
  const float* qnw  = (const float*)d_in[10];
  const float* knw  = (const float*)d_in[11];
  const float* alog = (const float*)d_in[12];

  char* ws = (char*)d_ws;
  float* q_projf = (float*)ws;                         // 33,554,432 B
  float* k_projf = (float*)(ws + 33554432);            //  8,388,608 B
  short* Vt      = (short*)(ws + 41943040);            //  4,456,448 B
  short* Qr      = (short*)(ws + 46399488);            // 16,777,216 B
  short* Kr      = (short*)(ws + 63176704);            //  4,456,448 B
  short* Xb      = (short*)(ws + 67633152);            // 16,777,216 B
  short* Wall    = (short*)(ws + 84410368);            // 50,331,648 B  (Wq|Wk|Wv)^T
  short* Wot     = Wall;                               // reused after QKV gemm
  short* attn_out = (short*)ws;                        // reuses q_projf (bf16)
  float* outp = (float*)d_out;

  const float qscale = 0.08838834764831845f;           // 128^-0.5

  dim3 blk(256);
  convert_x<<<dim3(T_SEQ * DMODEL / 8 / 256), blk, 0, stream>>>(hidden, Xb);
  transpose_convert<<<dim3(64, 64), blk, 0, stream>>>(Wq, Wall, DMODEL, 4096);
  transpose_convert<<<dim3(16, 64), blk, 0, stream>>>(Wk, Wall + (size_t)4096 * DMODEL, DMODEL, 1024);
  transpose_convert<<<dim3(16, 64), blk, 0, stream>>>(Wv, Wall + (size_t)5120 * DMODEL, DMODEL, 1024);
  gemm_qkv<<<dim3(32, 8), dim3(512), 0, stream>>>(Xb, Wall, q_projf, k_projf, Vt, DMODEL);
  rope_kernel<<<dim3(T_SEQ * NH / 4),  blk, 0, stream>>>(q_projf, qnw, cosT, sinT, Qr, 5, T_SEQ, 0, qscale);
  rope_kernel<<<dim3(T_SEQ * NKV / 4), blk, 0, stream>>>(k_projf, knw, cosT, sinT, Kr, 3, TKV, RVIRT, 1.0f);
  inject_kernel<<<dim3(NKV * RVIRT * HD / 256), blk, 0, stream>>>(vk, vv, alog, Kr, Vt);
  attn_kernel<<<dim3(16, NH), blk, 0, stream>>>(Qr, Kr, Vt, attn_out);
  transpose_convert<<<dim3(64, 64), blk, 0, stream>>>(Wo, Wot, 4096, 4096);
  gemm_out<<<dim3(16, 16), dim3(512), 0, stream>>>(attn_out, Wot, outp, 4096);
}